// Round 4
// baseline (2504.025 us; speedup 1.0000x reference)
//
#include <hip/hip_runtime.h>
#include <hip/hip_bf16.h>

// Problem constants
#define NB 4
#define SS 2048
#define HH 1024
#define EE 8
#define KK 2
#define DFF 2730
#define DFFP 2816           // 11*256; DFFP/64=44 even
#define NT (NB*SS)          // 8192 tokens
#define NA (NT*KK)          // 16384 assignments
#define YSZ ((size_t)NT*HH) // 8388608

using bf16x8 = __attribute__((ext_vector_type(8))) short;
using f32x4  = __attribute__((ext_vector_type(4))) float;

__device__ __forceinline__ ushort f2bf(float f) {
  unsigned u = __float_as_uint(f);
  unsigned r = (u + 0x7FFFu + ((u >> 16) & 1u)) >> 16;
  return (ushort)r;
}

__device__ __forceinline__ void gload16(const ushort* g, ushort* s) {
  __builtin_amdgcn_global_load_lds((const __attribute__((address_space(1))) void*)g,
                                   (__attribute__((address_space(3))) void*)s, 16, 0, 0);
}

// ---------------- x fp32 -> bf16 ----------------
__global__ __launch_bounds__(256) void cvt_x_kernel(const float4* __restrict__ x4,
                                                    ushort4* __restrict__ o4, int n4) {
  int i = blockIdx.x * 256 + threadIdx.x;
  if (i >= n4) return;
  float4 v = x4[i];
  ushort4 o;
  o.x = f2bf(v.x); o.y = f2bf(v.y); o.z = f2bf(v.z); o.w = f2bf(v.w);
  o4[i] = o;
}

// ------------- transpose + convert: in[e][K][Nn] fp32 -> out[e][Nnpad][Kpad] bf16 -------------
// write side fully vectorized (ushort4, coalesced 128B per 16 lanes)
__global__ __launch_bounds__(256) void transpose_cvt_kernel(
    const float* __restrict__ in, ushort* __restrict__ out,
    int K, int Nn, int Kpad, int Nnpad, long in_estride, long out_estride) {
  __shared__ float t[64][65];   // t[k_local][n_local]
  int e = blockIdx.z;
  const float* ine = in + (size_t)e * in_estride;
  ushort* oute = out + (size_t)e * out_estride;
  int nb = blockIdx.x * 64, kb = blockIdx.y * 64;
  int tid = threadIdx.x;
  int rr = tid >> 4, cc = (tid & 15) * 4;
  if (kb + 64 <= K && nb + 64 <= Nn) {
    // fast path: float2 vector loads (rows 8B-aligned for all relevant Nn)
#pragma unroll
    for (int i = 0; i < 4; ++i) {
      int r = rr + i * 16;
      const float* src = ine + (size_t)(kb + r) * Nn + nb + cc;
      float2 a = *(const float2*)src;
      float2 b = *(const float2*)(src + 2);
      t[r][cc] = a.x; t[r][cc + 1] = a.y; t[r][cc + 2] = b.x; t[r][cc + 3] = b.y;
    }
  } else {
#pragma unroll
    for (int i = 0; i < 4; ++i) {
      int r = rr + i * 16;
      int kg = kb + r;
#pragma unroll
      for (int j = 0; j < 4; ++j) {
        int ng = nb + cc + j;
        t[r][cc + j] = (kg < K && ng < Nn) ? ine[(size_t)kg * Nn + ng] : 0.0f;
      }
    }
  }
  __syncthreads();
  // write: lane group covers 64 consecutive kg (x2B = 128B) per row
  int kq = tid & 15;
#pragma unroll
  for (int i = 0; i < 4; ++i) {
    int nl = rr + i * 16, ng = nb + nl;
    ushort4 v;
    v.x = f2bf(t[kq * 4 + 0][nl]);
    v.y = f2bf(t[kq * 4 + 1][nl]);
    v.z = f2bf(t[kq * 4 + 2][nl]);
    v.w = f2bf(t[kq * 4 + 3][nl]);
    *(ushort4*)&oute[(size_t)ng * Kpad + kb + kq * 4] = v;
  }
}

// ---------------- router: logits, top2, counts ----------------
__global__ __launch_bounds__(256) void router_kernel(
    const float* __restrict__ x, const float* __restrict__ Wr, const float* __restrict__ br,
    float* __restrict__ logits_out, int* __restrict__ counts,
    int* __restrict__ tok_e, float* __restrict__ tok_w) {
  int wv = threadIdx.x >> 6, l = threadIdx.x & 63;
  int n = blockIdx.x * 4 + wv;
  const float* xr = x + (size_t)n * HH;
  float acc[8] = {0, 0, 0, 0, 0, 0, 0, 0};
#pragma unroll 4
  for (int i = 0; i < 16; ++i) {
    int k = l + i * 64;
    float xv = xr[k];
    const float4* w4 = (const float4*)(Wr + (size_t)k * 8);
    float4 a = w4[0], b = w4[1];
    acc[0] += xv * a.x; acc[1] += xv * a.y; acc[2] += xv * a.z; acc[3] += xv * a.w;
    acc[4] += xv * b.x; acc[5] += xv * b.y; acc[6] += xv * b.z; acc[7] += xv * b.w;
  }
#pragma unroll
  for (int s = 1; s < 64; s <<= 1)
#pragma unroll
    for (int e2 = 0; e2 < 8; ++e2) acc[e2] += __shfl_xor(acc[e2], s);
#pragma unroll
  for (int e2 = 0; e2 < 8; ++e2) acc[e2] += br[e2];
  if (l < 8) logits_out[(size_t)n * 8 + l] = acc[l];
  if (l == 0) {
    int i0 = 0;
#pragma unroll
    for (int e2 = 1; e2 < 8; ++e2) if (acc[e2] > acc[i0]) i0 = e2;
    int i1 = (i0 == 0) ? 1 : 0;
#pragma unroll
    for (int e2 = 0; e2 < 8; ++e2) if (e2 != i0 && acc[e2] > acc[i1]) i1 = e2;
    float e10 = __expf(acc[i1] - acc[i0]);
    float w0 = 1.0f / (1.0f + e10);
    tok_e[2 * n] = i0; tok_e[2 * n + 1] = i1;
    tok_w[2 * n] = w0; tok_w[2 * n + 1] = e10 / (1.0f + e10);
    atomicAdd(&counts[i0], 1); atomicAdd(&counts[i1], 1);
  }
}

__global__ void prefix_kernel(const int* __restrict__ counts, int* __restrict__ bases,
                              int* __restrict__ cursor) {
  if (threadIdx.x == 0) {
    int s = 0;
    for (int e = 0; e < EE; ++e) { bases[e] = s; s += counts[e]; }
    bases[EE] = s;
  }
  if (threadIdx.x < EE) cursor[threadIdx.x] = 0;
}

__global__ __launch_bounds__(256) void scatter_kernel(
    const int* __restrict__ tok_e, const float* __restrict__ tok_w,
    const int* __restrict__ bases, int* __restrict__ cursor,
    int* __restrict__ assign_token, float* __restrict__ assign_w) {
  int n = blockIdx.x * 256 + threadIdx.x;
  if (n >= NT) return;
#pragma unroll
  for (int k2 = 0; k2 < 2; ++k2) {
    int e = tok_e[2 * n + k2];
    int pos = atomicAdd(&cursor[e], 1);
    int slot = bases[e] + pos;
    assign_token[slot] = n;
    assign_w[slot] = tok_w[2 * n + k2];
  }
}

// ---------------- grouped GEMM v4: 256xBNT tile, BK=64, single-buffer, multi-block overlap ----
// 1D grid, XCD-bijective swizzle, (e [,kc], n) outer / m fastest -> same-XCD blocks share B panel.
// MODE 0: C = gather(xb) @ Wgt^T + bg  -> g (bf16)          BNT=128, 3 blocks/CU
// MODE 1: C = g @ Wut^T + bu, silu     -> u (bf16)          BNT=256, 2 blocks/CU
// MODE 2: C = u @ Wdt^T + bd, y += w*C (atomic, split-K=2)  BNT=256, 2 blocks/CU
template <int MODE, int BNT, int NBT, int KSPLIT>
__global__ __launch_bounds__(512, 4) void moe_gemm_v4(
    const ushort* __restrict__ Abase, const ushort* __restrict__ Wbase,
    const float* __restrict__ bias, ushort* __restrict__ outb, float* __restrict__ y,
    const int* __restrict__ bases, const int* __restrict__ assign_token,
    const float* __restrict__ assign_w,
    int K, int lda, long wstride_e, int bias_stride, int ldc,
    int ncols_valid, int ncols_write) {
  constexpr int NF = BNT / 64;    // n-fragments per wave; also B stage instrs per wave
  // ---- XCD-bijective swizzle (grid size % 8 == 0 by construction) ----
  int nwg = gridDim.x, q = nwg >> 3;
  int orig = blockIdx.x;
  int id = (orig & 7) * q + (orig >> 3);
  int m = id & 15; id >>= 4;
  int n = id % NBT; id /= NBT;
  int kc = (KSPLIT > 1) ? (id % KSPLIT) : 0;
  int e  = (KSPLIT > 1) ? (id / KSPLIT) : id;

  int base = bases[e], Ce = bases[e + 1] - base;
  int m0 = m * 256;
  if (m0 >= Ce) return;
  int n0 = n * BNT;
  int rows_valid = Ce - m0; if (rows_valid > 256) rows_valid = 256;
  int kch = K / KSPLIT;
  int k_begin = kc * kch;

  __shared__ ushort lds[256 * 64 + BNT * 64];
  constexpr int BOFF = 256 * 64;
  int tid = threadIdx.x, w = tid >> 6, l = tid & 63;
  int wm = w >> 2, wn = w & 3;
  const ushort* We = Wbase + (size_t)e * wstride_e;

  // staging: per wave-instr, 8 rows x 8 chunks (16B). dest linear, src chunk pre-swizzled
  int csrc = ((l & 7) ^ ((l >> 3) & 7)) * 8;
  int rl = l >> 3;
  const ushort* aP[4]; const ushort* bP[NF];
  int adst[4], bdst[NF];
#pragma unroll
  for (int i = 0; i < 4; ++i) {
    int r = w * 8 + i * 64 + rl;
    int ar = r < rows_valid ? r : rows_valid - 1;
    long arow = (MODE == 0) ? (long)assign_token[base + m0 + ar] : (long)(base + m0 + ar);
    aP[i] = Abase + arow * (long)lda + k_begin + csrc;
    adst[i] = (w * 8 + i * 64) * 64;
  }
#pragma unroll
  for (int i = 0; i < NF; ++i) {
    int r = w * 8 + i * 64 + rl;
    int wr = n0 + r; if (wr >= ncols_write) wr = ncols_write - 1;
    bP[i] = We + (size_t)wr * K + k_begin + csrc;
    bdst[i] = BOFF + (w * 8 + i * 64) * 64;
  }

  f32x4 acc[8][NF];
#pragma unroll
  for (int a1 = 0; a1 < 8; ++a1)
#pragma unroll
    for (int b1 = 0; b1 < NF; ++b1) acc[a1][b1] = f32x4{0.f, 0.f, 0.f, 0.f};

  int l15 = l & 15, lhi = l >> 4, l7 = l & 7;
  int nsteps = kch >> 6;
  for (int t = 0; t < nsteps; ++t) {
    int ko = t << 6;
#pragma unroll
    for (int i = 0; i < 4; ++i) gload16(aP[i] + ko, &lds[adst[i]]);
#pragma unroll
    for (int i = 0; i < NF; ++i) gload16(bP[i] + ko, &lds[bdst[i]]);
    __syncthreads();   // drains vmcnt(0): tile staged
#pragma unroll
    for (int ks = 0; ks < 2; ++ks) {
      bf16x8 af[8], bfr[NF];
#pragma unroll
      for (int mt = 0; mt < 8; ++mt) {
        int row = wm * 128 + mt * 16 + l15;
        int c = (ks * 4 + lhi) ^ l7;
        af[mt] = *(const bf16x8*)&lds[row * 64 + c * 8];
      }
#pragma unroll
      for (int nt = 0; nt < NF; ++nt) {
        int row = wn * (BNT / 4) + nt * 16 + l15;
        int c = (ks * 4 + lhi) ^ l7;
        bfr[nt] = *(const bf16x8*)&lds[BOFF + row * 64 + c * 8];
      }
#pragma unroll
      for (int mt = 0; mt < 8; ++mt)
#pragma unroll
        for (int nt = 0; nt < NF; ++nt)
          acc[mt][nt] = __builtin_amdgcn_mfma_f32_16x16x32_bf16(af[mt], bfr[nt], acc[mt][nt], 0, 0, 0);
    }
    __syncthreads();   // all reads done before next-step overwrite
  }

  // ---- epilogue ----
  int lr = l >> 4, lc = l & 15;
#pragma unroll
  for (int mt = 0; mt < 8; ++mt) {
#pragma unroll
    for (int i2 = 0; i2 < 4; ++i2) {
      int r = wm * 128 + mt * 16 + lr * 4 + i2;
      if (r >= rows_valid) continue;
      int slot = base + m0 + r;
      int tok = 0; float wgt = 0.f;
      if (MODE == 2) { tok = assign_token[slot]; wgt = assign_w[slot]; }
#pragma unroll
      for (int nt = 0; nt < NF; ++nt) {
        int col = n0 + wn * (BNT / 4) + nt * 16 + lc;
        if (col >= ncols_write) continue;
        float v = acc[mt][nt][i2];
        if (MODE == 0) {
          v += bias[e * bias_stride + col];
          outb[(size_t)slot * ldc + col] = f2bf(v);
        } else if (MODE == 1) {
          float o = 0.0f;
          if (col < ncols_valid) {
            v += bias[e * bias_stride + col];
            o = v / (1.0f + __expf(-v));
          }
          outb[(size_t)slot * ldc + col] = f2bf(o);
        } else {
          if (kc == 0) v += bias[e * bias_stride + col];
          atomicAdd(&y[(size_t)tok * HH + col], wgt * v);
        }
      }
    }
  }
}

extern "C" void kernel_launch(void* const* d_in, const int* in_sizes, int n_in,
                              void* d_out, int out_size, void* d_ws, size_t ws_size,
                              hipStream_t stream) {
  const float* x  = (const float*)d_in[0];
  const float* Wr = (const float*)d_in[1];
  const float* br = (const float*)d_in[2];
  const float* Wg = (const float*)d_in[3];
  const float* bg = (const float*)d_in[4];
  const float* Wu = (const float*)d_in[5];
  const float* bu = (const float*)d_in[6];
  const float* Wd = (const float*)d_in[7];
  const float* bd = (const float*)d_in[8];
  float* y = (float*)d_out;
  float* logits = y + YSZ;

  // workspace layout (bytes)
  char* ws = (char*)d_ws;
  size_t o = 0;
  auto alloc = [&](size_t b) { size_t r = o; o = (o + b + 255) & ~(size_t)255; return r; };
  size_t XB  = alloc((size_t)NT * HH * 2);
  size_t WGT = alloc((size_t)EE * HH * HH * 2);
  size_t WUT = alloc((size_t)EE * DFFP * HH * 2);
  size_t WDT = alloc((size_t)EE * HH * DFFP * 2);
  size_t G   = alloc((size_t)NA * HH * 2);
  size_t U   = alloc((size_t)NA * DFFP * 2);
  size_t META = alloc(262400);

  ushort* xb  = (ushort*)(ws + XB);
  ushort* wgt = (ushort*)(ws + WGT);
  ushort* wut = (ushort*)(ws + WUT);
  ushort* wdt = (ushort*)(ws + WDT);
  ushort* g   = (ushort*)(ws + G);
  ushort* u   = (ushort*)(ws + U);
  int* meta = (int*)(ws + META);
  int* counts = meta;                 // 8
  int* bases  = meta + 16;            // 9
  int* cursor = meta + 32;            // 8
  int* tok_e  = meta + 64;            // 16384
  float* tok_w = (float*)(tok_e + NA);
  int* assign_token = (int*)(tok_w + NA);
  float* assign_w = (float*)(assign_token + NA);

  hipMemsetAsync(y, 0, YSZ * sizeof(float), stream);
  hipMemsetAsync(meta, 0, 256, stream);

  // conversions
  cvt_x_kernel<<<(NT * HH / 4 + 255) / 256, 256, 0, stream>>>((const float4*)x, (ushort4*)xb, NT * HH / 4);
  transpose_cvt_kernel<<<dim3(16, 16, EE), 256, 0, stream>>>(Wg, wgt, HH, HH, HH, HH,
                                                             (long)HH * HH, (long)HH * HH);
  transpose_cvt_kernel<<<dim3(DFFP / 64, 16, EE), 256, 0, stream>>>(Wu, wut, HH, DFF, HH, DFFP,
                                                                    (long)HH * DFF, (long)DFFP * HH);
  transpose_cvt_kernel<<<dim3(16, DFFP / 64, EE), 256, 0, stream>>>(Wd, wdt, DFF, HH, DFFP, HH,
                                                                    (long)DFF * HH, (long)HH * DFFP);
  // routing
  router_kernel<<<NT / 4, 256, 0, stream>>>(x, Wr, br, logits, counts, tok_e, tok_w);
  prefix_kernel<<<1, 64, 0, stream>>>(counts, bases, cursor);
  scatter_kernel<<<NT / 256, 256, 0, stream>>>(tok_e, tok_w, bases, cursor, assign_token, assign_w);

  // expert MLP (grouped GEMMs)
  // MODE0: BNT=128, nb=8, grid 16*8*8 = 1024
  moe_gemm_v4<0, 128, 8, 1><<<1024, 512, 0, stream>>>(
      xb, wgt, bg, g, nullptr, bases, assign_token, assign_w,
      HH, HH, (long)HH * HH, HH, HH, HH, HH);
  // MODE1: BNT=256, nb=11, grid 16*11*8 = 1408
  moe_gemm_v4<1, 256, 11, 1><<<1408, 512, 0, stream>>>(
      g, wut, bu, u, nullptr, bases, assign_token, assign_w,
      HH, HH, (long)DFFP * HH, DFF, DFFP, DFF, DFFP);
  // MODE2: BNT=256, nb=4, split-K=2, grid 16*4*2*8 = 1024
  moe_gemm_v4<2, 256, 4, 2><<<1024, 512, 0, stream>>>(
      u, wdt, bd, nullptr, y, bases, assign_token, assign_w,
      DFFP, DFFP, (long)HH * DFFP, HH, HH, HH, HH);
}

// Round 5
// 1163.314 us; speedup vs baseline: 2.1525x; 2.1525x over previous
//
#include <hip/hip_runtime.h>
#include <hip/hip_bf16.h>

// Problem constants
#define NB 4
#define SS 2048
#define HH 1024
#define EE 8
#define KK 2
#define DFF 2730
#define DFFP 2752           // padded to multiple of 64
#define NT (NB*SS)          // 8192 tokens
#define NA (NT*KK)          // 16384 assignments
#define YSZ ((size_t)NT*HH) // 8388608

using bf16x8 = __attribute__((ext_vector_type(8))) short;
using f32x4  = __attribute__((ext_vector_type(4))) float;

__device__ __forceinline__ ushort f2bf(float f) {
  unsigned u = __float_as_uint(f);
  unsigned r = (u + 0x7FFFu + ((u >> 16) & 1u)) >> 16;
  return (ushort)r;
}

__device__ __forceinline__ void gload16(const ushort* g, ushort* s) {
  __builtin_amdgcn_global_load_lds((const __attribute__((address_space(1))) void*)g,
                                   (__attribute__((address_space(3))) void*)s, 16, 0, 0);
}

// ---------------- x fp32 -> bf16 ----------------
__global__ __launch_bounds__(256) void cvt_x_kernel(const float4* __restrict__ x4,
                                                    ushort4* __restrict__ o4, int n4) {
  int i = blockIdx.x * 256 + threadIdx.x;
  if (i >= n4) return;
  float4 v = x4[i];
  ushort4 o;
  o.x = f2bf(v.x); o.y = f2bf(v.y); o.z = f2bf(v.z); o.w = f2bf(v.w);
  o4[i] = o;
}

// ------------- transpose + convert: in[e][K][Nn] fp32 -> out[e][Nnpad][Kpad] bf16 -------------
// write side vectorized (ushort4, coalesced)
__global__ __launch_bounds__(256) void transpose_cvt_kernel(
    const float* __restrict__ in, ushort* __restrict__ out,
    int K, int Nn, int Kpad, int Nnpad, long in_estride, long out_estride) {
  __shared__ float t[64][65];   // t[k_local][n_local]
  int e = blockIdx.z;
  const float* ine = in + (size_t)e * in_estride;
  ushort* oute = out + (size_t)e * out_estride;
  int nb = blockIdx.x * 64, kb = blockIdx.y * 64;
  int tid = threadIdx.x;
  int rr = tid >> 4, cc = (tid & 15) * 4;
  if (kb + 64 <= K && nb + 64 <= Nn) {
#pragma unroll
    for (int i = 0; i < 4; ++i) {
      int r = rr + i * 16;
      const float* src = ine + (size_t)(kb + r) * Nn + nb + cc;
      float2 a = *(const float2*)src;
      float2 b = *(const float2*)(src + 2);
      t[r][cc] = a.x; t[r][cc + 1] = a.y; t[r][cc + 2] = b.x; t[r][cc + 3] = b.y;
    }
  } else {
#pragma unroll
    for (int i = 0; i < 4; ++i) {
      int r = rr + i * 16;
      int kg = kb + r;
#pragma unroll
      for (int j = 0; j < 4; ++j) {
        int ng = nb + cc + j;
        t[r][cc + j] = (kg < K && ng < Nn) ? ine[(size_t)kg * Nn + ng] : 0.0f;
      }
    }
  }
  __syncthreads();
  int kq = tid & 15;
#pragma unroll
  for (int i = 0; i < 4; ++i) {
    int nl = rr + i * 16, ng = nb + nl;
    ushort4 v;
    v.x = f2bf(t[kq * 4 + 0][nl]);
    v.y = f2bf(t[kq * 4 + 1][nl]);
    v.z = f2bf(t[kq * 4 + 2][nl]);
    v.w = f2bf(t[kq * 4 + 3][nl]);
    *(ushort4*)&oute[(size_t)ng * Kpad + kb + kq * 4] = v;
  }
}

// ---------------- router: logits, top2, counts ----------------
__global__ __launch_bounds__(256) void router_kernel(
    const float* __restrict__ x, const float* __restrict__ Wr, const float* __restrict__ br,
    float* __restrict__ logits_out, int* __restrict__ counts,
    int* __restrict__ tok_e, float* __restrict__ tok_w) {
  int wv = threadIdx.x >> 6, l = threadIdx.x & 63;
  int n = blockIdx.x * 4 + wv;
  const float* xr = x + (size_t)n * HH;
  float acc[8] = {0, 0, 0, 0, 0, 0, 0, 0};
#pragma unroll 4
  for (int i = 0; i < 16; ++i) {
    int k = l + i * 64;
    float xv = xr[k];
    const float4* w4 = (const float4*)(Wr + (size_t)k * 8);
    float4 a = w4[0], b = w4[1];
    acc[0] += xv * a.x; acc[1] += xv * a.y; acc[2] += xv * a.z; acc[3] += xv * a.w;
    acc[4] += xv * b.x; acc[5] += xv * b.y; acc[6] += xv * b.z; acc[7] += xv * b.w;
  }
#pragma unroll
  for (int s = 1; s < 64; s <<= 1)
#pragma unroll
    for (int e2 = 0; e2 < 8; ++e2) acc[e2] += __shfl_xor(acc[e2], s);
#pragma unroll
  for (int e2 = 0; e2 < 8; ++e2) acc[e2] += br[e2];
  if (l < 8) logits_out[(size_t)n * 8 + l] = acc[l];
  if (l == 0) {
    int i0 = 0;
#pragma unroll
    for (int e2 = 1; e2 < 8; ++e2) if (acc[e2] > acc[i0]) i0 = e2;
    int i1 = (i0 == 0) ? 1 : 0;
#pragma unroll
    for (int e2 = 0; e2 < 8; ++e2) if (e2 != i0 && acc[e2] > acc[i1]) i1 = e2;
    float e10 = __expf(acc[i1] - acc[i0]);
    float w0 = 1.0f / (1.0f + e10);
    tok_e[2 * n] = i0; tok_e[2 * n + 1] = i1;
    tok_w[2 * n] = w0; tok_w[2 * n + 1] = e10 / (1.0f + e10);
    atomicAdd(&counts[i0], 1); atomicAdd(&counts[i1], 1);
  }
}

__global__ void prefix_kernel(const int* __restrict__ counts, int* __restrict__ bases,
                              int* __restrict__ cursor) {
  if (threadIdx.x == 0) {
    int s = 0;
    for (int e = 0; e < EE; ++e) { bases[e] = s; s += counts[e]; }
    bases[EE] = s;
  }
  if (threadIdx.x < EE) cursor[threadIdx.x] = 0;
}

__global__ __launch_bounds__(256) void scatter_kernel(
    const int* __restrict__ tok_e, const float* __restrict__ tok_w,
    const int* __restrict__ bases, int* __restrict__ cursor,
    int* __restrict__ assign_token, float* __restrict__ assign_w) {
  int n = blockIdx.x * 256 + threadIdx.x;
  if (n >= NT) return;
#pragma unroll
  for (int k2 = 0; k2 < 2; ++k2) {
    int e = tok_e[2 * n + k2];
    int pos = atomicAdd(&cursor[e], 1);
    int slot = bases[e] + pos;
    assign_token[slot] = n;
    assign_w[slot] = tok_w[2 * n + k2];
  }
}

// ---------------- grouped GEMM, 128x128 tile, BK=64, dbuf + pinned overlap ----------------
// Per K-step: [STAGE(t+1) x8 gload16] sched_barrier [ds_read+MFMA] sched_barrier
//             vmcnt(0) raw-s_barrier.  (m230/T3-minimal recipe)
// MODE 0: C = gather(xb) @ Wgt^T + bg  -> g (bf16)
// MODE 1: C = g @ Wut^T + bu, silu     -> u (bf16, cols >= DFF zeroed)
// MODE 2: C = u @ Wdt^T + bd, y[tok] += w*C (atomic fp32)
template <int MODE>
__global__ __launch_bounds__(256, 2) void moe_gemm_kernel(
    const ushort* __restrict__ Abase, const ushort* __restrict__ Wbase,
    const float* __restrict__ bias, ushort* __restrict__ outb, float* __restrict__ y,
    const int* __restrict__ bases, const int* __restrict__ assign_token,
    const float* __restrict__ assign_w,
    int K, int lda, long wstride_e, int bias_stride, int ldc,
    int ncols_valid, int ncols_write, int wrows) {
  int e = blockIdx.z;
  int base = bases[e], Ce = bases[e + 1] - base;
  int m0 = blockIdx.x * 128;
  if (m0 >= Ce) return;
  int n0 = blockIdx.y * 128;
  int rows_valid = Ce - m0; if (rows_valid > 128) rows_valid = 128;

  // dbuf: buf b -> A at b*16384, B at b*16384+8192 (ushort idx). 64 KiB total.
  __shared__ ushort lds[32768];
  int tid = threadIdx.x, w = tid >> 6, l = tid & 63;
  int wm = w >> 1, wn = w & 1;

  const ushort* aptr[4];
  const ushort* bptr[4];
  int lofs[4];
  const ushort* We = Wbase + (size_t)e * wstride_e;
#pragma unroll
  for (int i = 0; i < 4; ++i) {
    int s = i * 4 + w;
    int chunk = s * 64 + l;
    int r = chunk >> 3, cir = chunk & 7;
    int cirs = cir ^ (r & 7);
    int ar = r < rows_valid ? r : rows_valid - 1;
    int slot = base + m0 + ar;
    long arow = (MODE == 0) ? (long)assign_token[slot] : (long)slot;
    aptr[i] = Abase + arow * (long)lda + cirs * 8;
    int wr = n0 + r; if (wr >= wrows) wr = wrows - 1;
    bptr[i] = We + (size_t)wr * K + cirs * 8;
    lofs[i] = s * 512;
  }

  f32x4 acc[4][4];
#pragma unroll
  for (int a1 = 0; a1 < 4; ++a1)
#pragma unroll
    for (int b1 = 0; b1 < 4; ++b1) acc[a1][b1] = f32x4{0.f, 0.f, 0.f, 0.f};

  int nk = K >> 6;
  // prologue: stage tile 0 -> buf 0, full drain
#pragma unroll
  for (int i = 0; i < 4; ++i) {
    gload16(aptr[i], &lds[lofs[i]]);
    gload16(bptr[i], &lds[8192 + lofs[i]]);
  }
  asm volatile("s_waitcnt vmcnt(0)" ::: "memory");
  __builtin_amdgcn_s_barrier();

  int cur = 0;
  for (int t = 0; t < nk; ++t) {
    int nxt = cur ^ 1;
    if (t + 1 < nk) {
      int k0 = (t + 1) << 6;
#pragma unroll
      for (int i = 0; i < 4; ++i) {
        gload16(aptr[i] + k0, &lds[nxt * 16384 + lofs[i]]);
        gload16(bptr[i] + k0, &lds[nxt * 16384 + 8192 + lofs[i]]);
      }
    }
    __builtin_amdgcn_sched_barrier(0);   // pin: stage issued BEFORE compute
    const ushort* cA = &lds[cur * 16384];
    const ushort* cB = &lds[cur * 16384 + 8192];
#pragma unroll
    for (int ks = 0; ks < 2; ++ks) {
      bf16x8 af[4], bfr[4];
#pragma unroll
      for (int mt = 0; mt < 4; ++mt) {
        int row = wm * 64 + mt * 16 + (l & 15);
        int cir = (ks * 4 + (l >> 4)) ^ (row & 7);
        af[mt] = *(const bf16x8*)&cA[row * 64 + cir * 8];
      }
#pragma unroll
      for (int nt = 0; nt < 4; ++nt) {
        int row = wn * 64 + nt * 16 + (l & 15);
        int cir = (ks * 4 + (l >> 4)) ^ (row & 7);
        bfr[nt] = *(const bf16x8*)&cB[row * 64 + cir * 8];
      }
#pragma unroll
      for (int mt = 0; mt < 4; ++mt)
#pragma unroll
        for (int nt = 0; nt < 4; ++nt)
          acc[mt][nt] = __builtin_amdgcn_mfma_f32_16x16x32_bf16(af[mt], bfr[nt], acc[mt][nt], 0, 0, 0);
    }
    __builtin_amdgcn_sched_barrier(0);   // pin: compute done before drain
    asm volatile("s_waitcnt vmcnt(0)" ::: "memory");  // t+1 loads landed (hidden under MFMA)
    __builtin_amdgcn_s_barrier();
    cur = nxt;
  }

  int lr = l >> 4, lc = l & 15;
#pragma unroll
  for (int mt = 0; mt < 4; ++mt) {
#pragma unroll
    for (int i2 = 0; i2 < 4; ++i2) {
      int r = wm * 64 + mt * 16 + lr * 4 + i2;
      if (r >= rows_valid) continue;
      int slot = base + m0 + r;
      int tok = 0; float wgt = 0.f;
      if (MODE == 2) { tok = assign_token[slot]; wgt = assign_w[slot]; }
#pragma unroll
      for (int nt = 0; nt < 4; ++nt) {
        int col = n0 + wn * 64 + nt * 16 + lc;
        if (col >= ncols_write) continue;
        float v = acc[mt][nt][i2];
        if (MODE == 0) {
          v += bias[e * bias_stride + col];
          outb[(size_t)slot * ldc + col] = f2bf(v);
        } else if (MODE == 1) {
          float o = 0.0f;
          if (col < ncols_valid) {
            v += bias[e * bias_stride + col];
            o = v / (1.0f + __expf(-v));
          }
          outb[(size_t)slot * ldc + col] = f2bf(o);
        } else {
          v += bias[e * bias_stride + col];
          atomicAdd(&y[(size_t)tok * HH + col], wgt * v);
        }
      }
    }
  }
}

extern "C" void kernel_launch(void* const* d_in, const int* in_sizes, int n_in,
                              void* d_out, int out_size, void* d_ws, size_t ws_size,
                              hipStream_t stream) {
  const float* x  = (const float*)d_in[0];
  const float* Wr = (const float*)d_in[1];
  const float* br = (const float*)d_in[2];
  const float* Wg = (const float*)d_in[3];
  const float* bg = (const float*)d_in[4];
  const float* Wu = (const float*)d_in[5];
  const float* bu = (const float*)d_in[6];
  const float* Wd = (const float*)d_in[7];
  const float* bd = (const float*)d_in[8];
  float* y = (float*)d_out;
  float* logits = y + YSZ;

  // workspace layout (bytes)
  char* ws = (char*)d_ws;
  size_t o = 0;
  auto alloc = [&](size_t b) { size_t r = o; o = (o + b + 255) & ~(size_t)255; return r; };
  size_t XB  = alloc((size_t)NT * HH * 2);
  size_t WGT = alloc((size_t)EE * HH * HH * 2);
  size_t WUT = alloc((size_t)EE * DFFP * HH * 2);
  size_t WDT = alloc((size_t)EE * HH * DFFP * 2);
  size_t G   = alloc((size_t)NA * HH * 2);
  size_t U   = alloc((size_t)NA * DFFP * 2);
  size_t META = alloc(262400);

  ushort* xb  = (ushort*)(ws + XB);
  ushort* wgt = (ushort*)(ws + WGT);
  ushort* wut = (ushort*)(ws + WUT);
  ushort* wdt = (ushort*)(ws + WDT);
  ushort* g   = (ushort*)(ws + G);
  ushort* u   = (ushort*)(ws + U);
  int* meta = (int*)(ws + META);
  int* counts = meta;                 // 8
  int* bases  = meta + 16;            // 9
  int* cursor = meta + 32;            // 8
  int* tok_e  = meta + 64;            // 16384
  float* tok_w = (float*)(tok_e + NA);
  int* assign_token = (int*)(tok_w + NA);
  float* assign_w = (float*)(assign_token + NA);

  hipMemsetAsync(y, 0, YSZ * sizeof(float), stream);
  hipMemsetAsync(meta, 0, 256, stream);

  // conversions
  cvt_x_kernel<<<(NT * HH / 4 + 255) / 256, 256, 0, stream>>>((const float4*)x, (ushort4*)xb, NT * HH / 4);
  transpose_cvt_kernel<<<dim3(16, 16, EE), 256, 0, stream>>>(Wg, wgt, HH, HH, HH, HH,
                                                             (long)HH * HH, (long)HH * HH);
  transpose_cvt_kernel<<<dim3(DFFP / 64, 16, EE), 256, 0, stream>>>(Wu, wut, HH, DFF, HH, DFFP,
                                                                    (long)HH * DFF, (long)DFFP * HH);
  transpose_cvt_kernel<<<dim3(16, DFFP / 64, EE), 256, 0, stream>>>(Wd, wdt, DFF, HH, DFFP, HH,
                                                                    (long)DFF * HH, (long)HH * DFFP);
  // routing
  router_kernel<<<NT / 4, 256, 0, stream>>>(x, Wr, br, logits, counts, tok_e, tok_w);
  prefix_kernel<<<1, 64, 0, stream>>>(counts, bases, cursor);
  scatter_kernel<<<NT / 256, 256, 0, stream>>>(tok_e, tok_w, bases, cursor, assign_token, assign_w);

  // expert MLP (grouped GEMMs), 128x128 tiles
  moe_gemm_kernel<0><<<dim3(64, 8, EE), 256, 0, stream>>>(
      xb, wgt, bg, g, nullptr, bases, assign_token, assign_w,
      HH, HH, (long)HH * HH, HH, HH, HH, HH, HH);
  moe_gemm_kernel<1><<<dim3(64, DFFP / 128 + 1, EE), 256, 0, stream>>>(
      g, wut, bu, u, nullptr, bases, assign_token, assign_w,
      HH, HH, (long)DFFP * HH, DFF, DFFP, DFF, DFFP, DFFP);
  moe_gemm_kernel<2><<<dim3(64, 8, EE), 256, 0, stream>>>(
      u, wdt, bd, nullptr, y, bases, assign_token, assign_w,
      DFFP, DFFP, (long)HH * DFFP, HH, HH, HH, HH, HH);
}

// Round 6
// 895.061 us; speedup vs baseline: 2.7976x; 1.2997x over previous
//
#include <hip/hip_runtime.h>
#include <hip/hip_bf16.h>

// Problem constants
#define NB 4
#define SS 2048
#define HH 1024
#define EE 8
#define KK 2
#define DFF 2730
#define DFFP 2752           // padded to multiple of 64
#define NT (NB*SS)          // 8192 tokens
#define NA (NT*KK)          // 16384 assignments
#define YSZ ((size_t)NT*HH) // 8388608

using bf16x8 = __attribute__((ext_vector_type(8))) short;
using f32x4  = __attribute__((ext_vector_type(4))) float;

__device__ __forceinline__ ushort f2bf(float f) {
  unsigned u = __float_as_uint(f);
  unsigned r = (u + 0x7FFFu + ((u >> 16) & 1u)) >> 16;
  return (ushort)r;
}

__device__ __forceinline__ void gload16(const ushort* g, ushort* s) {
  __builtin_amdgcn_global_load_lds((const __attribute__((address_space(1))) void*)g,
                                   (__attribute__((address_space(3))) void*)s, 16, 0, 0);
}

// ---------------- x fp32 -> bf16 ----------------
__global__ __launch_bounds__(256) void cvt_x_kernel(const float4* __restrict__ x4,
                                                    ushort4* __restrict__ o4, int n4) {
  int i = blockIdx.x * 256 + threadIdx.x;
  if (i >= n4) return;
  float4 v = x4[i];
  ushort4 o;
  o.x = f2bf(v.x); o.y = f2bf(v.y); o.z = f2bf(v.z); o.w = f2bf(v.w);
  o4[i] = o;
}

// ------------- transpose + convert: in[e][K][Nn] fp32 -> out[e][Nnpad][Kpad] bf16 -------------
__global__ __launch_bounds__(256) void transpose_cvt_kernel(
    const float* __restrict__ in, ushort* __restrict__ out,
    int K, int Nn, int Kpad, int Nnpad, long in_estride, long out_estride) {
  __shared__ float t[64][65];   // t[k_local][n_local]
  int e = blockIdx.z;
  const float* ine = in + (size_t)e * in_estride;
  ushort* oute = out + (size_t)e * out_estride;
  int nb = blockIdx.x * 64, kb = blockIdx.y * 64;
  int tid = threadIdx.x;
  int rr = tid >> 4, cc = (tid & 15) * 4;
  if (kb + 64 <= K && nb + 64 <= Nn) {
#pragma unroll
    for (int i = 0; i < 4; ++i) {
      int r = rr + i * 16;
      const float* src = ine + (size_t)(kb + r) * Nn + nb + cc;
      float2 a = *(const float2*)src;
      float2 b = *(const float2*)(src + 2);
      t[r][cc] = a.x; t[r][cc + 1] = a.y; t[r][cc + 2] = b.x; t[r][cc + 3] = b.y;
    }
  } else {
#pragma unroll
    for (int i = 0; i < 4; ++i) {
      int r = rr + i * 16;
      int kg = kb + r;
#pragma unroll
      for (int j = 0; j < 4; ++j) {
        int ng = nb + cc + j;
        t[r][cc + j] = (kg < K && ng < Nn) ? ine[(size_t)kg * Nn + ng] : 0.0f;
      }
    }
  }
  __syncthreads();
  int kq = tid & 15;
#pragma unroll
  for (int i = 0; i < 4; ++i) {
    int nl = rr + i * 16, ng = nb + nl;
    ushort4 v;
    v.x = f2bf(t[kq * 4 + 0][nl]);
    v.y = f2bf(t[kq * 4 + 1][nl]);
    v.z = f2bf(t[kq * 4 + 2][nl]);
    v.w = f2bf(t[kq * 4 + 3][nl]);
    *(ushort4*)&oute[(size_t)ng * Kpad + kb + kq * 4] = v;
  }
}

// ---------------- router: logits, top2, counts ----------------
__global__ __launch_bounds__(256) void router_kernel(
    const float* __restrict__ x, const float* __restrict__ Wr, const float* __restrict__ br,
    float* __restrict__ logits_out, int* __restrict__ counts,
    int* __restrict__ tok_e, float* __restrict__ tok_w) {
  int wv = threadIdx.x >> 6, l = threadIdx.x & 63;
  int n = blockIdx.x * 4 + wv;
  const float* xr = x + (size_t)n * HH;
  float acc[8] = {0, 0, 0, 0, 0, 0, 0, 0};
#pragma unroll 4
  for (int i = 0; i < 16; ++i) {
    int k = l + i * 64;
    float xv = xr[k];
    const float4* w4 = (const float4*)(Wr + (size_t)k * 8);
    float4 a = w4[0], b = w4[1];
    acc[0] += xv * a.x; acc[1] += xv * a.y; acc[2] += xv * a.z; acc[3] += xv * a.w;
    acc[4] += xv * b.x; acc[5] += xv * b.y; acc[6] += xv * b.z; acc[7] += xv * b.w;
  }
#pragma unroll
  for (int s = 1; s < 64; s <<= 1)
#pragma unroll
    for (int e2 = 0; e2 < 8; ++e2) acc[e2] += __shfl_xor(acc[e2], s);
#pragma unroll
  for (int e2 = 0; e2 < 8; ++e2) acc[e2] += br[e2];
  if (l < 8) logits_out[(size_t)n * 8 + l] = acc[l];
  if (l == 0) {
    int i0 = 0;
#pragma unroll
    for (int e2 = 1; e2 < 8; ++e2) if (acc[e2] > acc[i0]) i0 = e2;
    int i1 = (i0 == 0) ? 1 : 0;
#pragma unroll
    for (int e2 = 0; e2 < 8; ++e2) if (e2 != i0 && acc[e2] > acc[i1]) i1 = e2;
    float e10 = __expf(acc[i1] - acc[i0]);
    float w0 = 1.0f / (1.0f + e10);
    tok_e[2 * n] = i0; tok_e[2 * n + 1] = i1;
    tok_w[2 * n] = w0; tok_w[2 * n + 1] = e10 / (1.0f + e10);
    atomicAdd(&counts[i0], 1); atomicAdd(&counts[i1], 1);
  }
}

__global__ void prefix_kernel(const int* __restrict__ counts, int* __restrict__ bases,
                              int* __restrict__ cursor) {
  if (threadIdx.x == 0) {
    int s = 0;
    for (int e = 0; e < EE; ++e) { bases[e] = s; s += counts[e]; }
    bases[EE] = s;
  }
  if (threadIdx.x < EE) cursor[threadIdx.x] = 0;
}

__global__ __launch_bounds__(256) void scatter_kernel(
    const int* __restrict__ tok_e, const float* __restrict__ tok_w,
    const int* __restrict__ bases, int* __restrict__ cursor,
    int* __restrict__ assign_token, float* __restrict__ assign_w) {
  int n = blockIdx.x * 256 + threadIdx.x;
  if (n >= NT) return;
#pragma unroll
  for (int k2 = 0; k2 < 2; ++k2) {
    int e = tok_e[2 * n + k2];
    int pos = atomicAdd(&cursor[e], 1);
    int slot = bases[e] + pos;
    assign_token[slot] = n;
    assign_w[slot] = tok_w[2 * n + k2];
  }
}

// ---------------- grouped GEMM, 128x128 tile, BK=64, T3-minimal 2-phase ----------------
// Per K-step: STAGE(t+1) -> [LDS reads + MFMA, compiler-scheduled] -> setprio around MFMA
//             -> vmcnt(0) -> raw s_barrier.  NO sched_barrier (m141).
// MODE 0: C = gather(xb) @ Wgt^T + bg  -> g (bf16)
// MODE 1: C = g @ Wut^T + bu, silu     -> u (bf16, cols >= DFF zeroed)
// MODE 2: C = u @ Wdt^T + bd, y[tok] += w*C (atomic fp32)
template <int MODE>
__global__ __launch_bounds__(256, 2) void moe_gemm_kernel(
    const ushort* __restrict__ Abase, const ushort* __restrict__ Wbase,
    const float* __restrict__ bias, ushort* __restrict__ outb, float* __restrict__ y,
    const int* __restrict__ bases, const int* __restrict__ assign_token,
    const float* __restrict__ assign_w,
    int K, int lda, long wstride_e, int bias_stride, int ldc,
    int ncols_valid, int ncols_write, int wrows) {
  int e = blockIdx.z;
  int base = bases[e], Ce = bases[e + 1] - base;
  int m0 = blockIdx.x * 128;
  if (m0 >= Ce) return;
  int n0 = blockIdx.y * 128;
  int rows_valid = Ce - m0; if (rows_valid > 128) rows_valid = 128;

  // dbuf: buf b -> A at b*16384, B at b*16384+8192 (ushort idx). 64 KiB total.
  __shared__ ushort lds[32768];
  int tid = threadIdx.x, w = tid >> 6, l = tid & 63;
  int wm = w >> 1, wn = w & 1;

  const ushort* aptr[4];
  const ushort* bptr[4];
  int lofs[4];
  const ushort* We = Wbase + (size_t)e * wstride_e;
#pragma unroll
  for (int i = 0; i < 4; ++i) {
    int s = i * 4 + w;
    int chunk = s * 64 + l;
    int r = chunk >> 3, cir = chunk & 7;
    int cirs = cir ^ (r & 7);
    int ar = r < rows_valid ? r : rows_valid - 1;
    int slot = base + m0 + ar;
    long arow = (MODE == 0) ? (long)assign_token[slot] : (long)slot;
    aptr[i] = Abase + arow * (long)lda + cirs * 8;
    int wr = n0 + r; if (wr >= wrows) wr = wrows - 1;
    bptr[i] = We + (size_t)wr * K + cirs * 8;
    lofs[i] = s * 512;
  }

  f32x4 acc[4][4];
#pragma unroll
  for (int a1 = 0; a1 < 4; ++a1)
#pragma unroll
    for (int b1 = 0; b1 < 4; ++b1) acc[a1][b1] = f32x4{0.f, 0.f, 0.f, 0.f};

  int nk = K >> 6;
  // prologue: stage tile 0 -> buf 0, full drain
#pragma unroll
  for (int i = 0; i < 4; ++i) {
    gload16(aptr[i], &lds[lofs[i]]);
    gload16(bptr[i], &lds[8192 + lofs[i]]);
  }
  asm volatile("s_waitcnt vmcnt(0)" ::: "memory");
  __builtin_amdgcn_s_barrier();

  int cur = 0;
  for (int t = 0; t < nk; ++t) {
    int nxt = cur ^ 1;
    if (t + 1 < nk) {
      int k0 = (t + 1) << 6;
#pragma unroll
      for (int i = 0; i < 4; ++i) {
        gload16(aptr[i] + k0, &lds[nxt * 16384 + lofs[i]]);
        gload16(bptr[i] + k0, &lds[nxt * 16384 + 8192 + lofs[i]]);
      }
    }
    const ushort* cA = &lds[cur * 16384];
    const ushort* cB = &lds[cur * 16384 + 8192];
#pragma unroll
    for (int ks = 0; ks < 2; ++ks) {
      bf16x8 af[4], bfr[4];
#pragma unroll
      for (int mt = 0; mt < 4; ++mt) {
        int row = wm * 64 + mt * 16 + (l & 15);
        int cir = (ks * 4 + (l >> 4)) ^ (row & 7);
        af[mt] = *(const bf16x8*)&cA[row * 64 + cir * 8];
      }
#pragma unroll
      for (int nt = 0; nt < 4; ++nt) {
        int row = wn * 64 + nt * 16 + (l & 15);
        int cir = (ks * 4 + (l >> 4)) ^ (row & 7);
        bfr[nt] = *(const bf16x8*)&cB[row * 64 + cir * 8];
      }
      __builtin_amdgcn_s_setprio(1);
#pragma unroll
      for (int mt = 0; mt < 4; ++mt)
#pragma unroll
        for (int nt = 0; nt < 4; ++nt)
          acc[mt][nt] = __builtin_amdgcn_mfma_f32_16x16x32_bf16(af[mt], bfr[nt], acc[mt][nt], 0, 0, 0);
      __builtin_amdgcn_s_setprio(0);
    }
    asm volatile("s_waitcnt vmcnt(0)" ::: "memory");  // t+1 staged (hidden under MFMA)
    __builtin_amdgcn_s_barrier();
    cur = nxt;
  }

  int lr = l >> 4, lc = l & 15;
#pragma unroll
  for (int mt = 0; mt < 4; ++mt) {
#pragma unroll
    for (int i2 = 0; i2 < 4; ++i2) {
      int r = wm * 64 + mt * 16 + lr * 4 + i2;
      if (r >= rows_valid) continue;
      int slot = base + m0 + r;
      int tok = 0; float wgt = 0.f;
      if (MODE == 2) { tok = assign_token[slot]; wgt = assign_w[slot]; }
#pragma unroll
      for (int nt = 0; nt < 4; ++nt) {
        int col = n0 + wn * 64 + nt * 16 + lc;
        if (col >= ncols_write) continue;
        float v = acc[mt][nt][i2];
        if (MODE == 0) {
          v += bias[e * bias_stride + col];
          outb[(size_t)slot * ldc + col] = f2bf(v);
        } else if (MODE == 1) {
          float o = 0.0f;
          if (col < ncols_valid) {
            v += bias[e * bias_stride + col];
            o = v / (1.0f + __expf(-v));
          }
          outb[(size_t)slot * ldc + col] = f2bf(o);
        } else {
          v += bias[e * bias_stride + col];
          atomicAdd(&y[(size_t)tok * HH + col], wgt * v);
        }
      }
    }
  }
}

extern "C" void kernel_launch(void* const* d_in, const int* in_sizes, int n_in,
                              void* d_out, int out_size, void* d_ws, size_t ws_size,
                              hipStream_t stream) {
  const float* x  = (const float*)d_in[0];
  const float* Wr = (const float*)d_in[1];
  const float* br = (const float*)d_in[2];
  const float* Wg = (const float*)d_in[3];
  const float* bg = (const float*)d_in[4];
  const float* Wu = (const float*)d_in[5];
  const float* bu = (const float*)d_in[6];
  const float* Wd = (const float*)d_in[7];
  const float* bd = (const float*)d_in[8];
  float* y = (float*)d_out;
  float* logits = y + YSZ;

  // workspace layout (bytes)
  char* ws = (char*)d_ws;
  size_t o = 0;
  auto alloc = [&](size_t b) { size_t r = o; o = (o + b + 255) & ~(size_t)255; return r; };
  size_t XB  = alloc((size_t)NT * HH * 2);
  size_t WGT = alloc((size_t)EE * HH * HH * 2);
  size_t WUT = alloc((size_t)EE * DFFP * HH * 2);
  size_t WDT = alloc((size_t)EE * HH * DFFP * 2);
  size_t G   = alloc((size_t)NA * HH * 2);
  size_t U   = alloc((size_t)NA * DFFP * 2);
  size_t META = alloc(262400);

  ushort* xb  = (ushort*)(ws + XB);
  ushort* wgt = (ushort*)(ws + WGT);
  ushort* wut = (ushort*)(ws + WUT);
  ushort* wdt = (ushort*)(ws + WDT);
  ushort* g   = (ushort*)(ws + G);
  ushort* u   = (ushort*)(ws + U);
  int* meta = (int*)(ws + META);
  int* counts = meta;                 // 8
  int* bases  = meta + 16;            // 9
  int* cursor = meta + 32;            // 8
  int* tok_e  = meta + 64;            // 16384
  float* tok_w = (float*)(tok_e + NA);
  int* assign_token = (int*)(tok_w + NA);
  float* assign_w = (float*)(assign_token + NA);

  hipMemsetAsync(y, 0, YSZ * sizeof(float), stream);
  hipMemsetAsync(meta, 0, 256, stream);

  // conversions
  cvt_x_kernel<<<(NT * HH / 4 + 255) / 256, 256, 0, stream>>>((const float4*)x, (ushort4*)xb, NT * HH / 4);
  transpose_cvt_kernel<<<dim3(16, 16, EE), 256, 0, stream>>>(Wg, wgt, HH, HH, HH, HH,
                                                             (long)HH * HH, (long)HH * HH);
  transpose_cvt_kernel<<<dim3(DFFP / 64, 16, EE), 256, 0, stream>>>(Wu, wut, HH, DFF, HH, DFFP,
                                                                    (long)HH * DFF, (long)DFFP * HH);
  transpose_cvt_kernel<<<dim3(16, DFFP / 64, EE), 256, 0, stream>>>(Wd, wdt, DFF, HH, DFFP, HH,
                                                                    (long)DFF * HH, (long)HH * DFFP);
  // routing
  router_kernel<<<NT / 4, 256, 0, stream>>>(x, Wr, br, logits, counts, tok_e, tok_w);
  prefix_kernel<<<1, 64, 0, stream>>>(counts, bases, cursor);
  scatter_kernel<<<NT / 256, 256, 0, stream>>>(tok_e, tok_w, bases, cursor, assign_token, assign_w);

  // expert MLP (grouped GEMMs), 128x128 tiles; 20 m-blocks = 2560-row headroom (+12 sigma)
  moe_gemm_kernel<0><<<dim3(20, 8, EE), 256, 0, stream>>>(
      xb, wgt, bg, g, nullptr, bases, assign_token, assign_w,
      HH, HH, (long)HH * HH, HH, HH, HH, HH, HH);
  moe_gemm_kernel<1><<<dim3(20, DFFP / 128 + 1, EE), 256, 0, stream>>>(
      g, wut, bu, u, nullptr, bases, assign_token, assign_w,
      HH, HH, (long)DFFP * HH, DFF, DFFP, DFF, DFFP, DFFP);
  moe_gemm_kernel<2><<<dim3(20, 8, EE), 256, 0, stream>>>(
      u, wdt, bd, nullptr, y, bases, assign_token, assign_w,
      DFFP, DFFP, (long)HH * DFFP, HH, HH, HH, HH, HH);
}